// Round 1
// baseline (444.630 us; speedup 1.0000x reference)
//
#include <hip/hip_runtime.h>
#include <cmath>

#define BB   8
#define NPIX 256
#define MM   8192
#define NCP  24576
#define NCA  24576
#define EPSF 1e-16f

#define TM 16    // m's per block
#define MT 2     // m's per thread (8 m-groups)
#define XT 8     // x's per thread (32 x-groups)

#define VIS_OFF    0
#define VISAMP_OFF (BB * 2 * MM)            // 131072
#define CPH_OFF    (VISAMP_OFF + BB * MM)   // 196608
#define LCA_OFF    (CPH_OFF + BB * NCP)     // 393216

// Main kernel: computes vis (B,2,M) and visamp (B,M) into d_out.
__global__ __launch_bounds__(256, 4)
void nufft_vis_kernel(const float* __restrict__ images,
                      const float* __restrict__ ktraj,
                      const float* __restrict__ pulsefac,
                      float* __restrict__ out)
{
    // Ev table: [m][y][re/im] interleaved, 16*256*2 floats = 32 KB
    __shared__ float ev[TM * NPIX * 2];

    const int tid = threadIdx.x;
    const int m0  = blockIdx.x * TM;
    const int xg  = tid & 31;     // x-group
    const int mg  = tid >> 5;     // m-group (0..7)
    const int x0  = xg * XT;

    // Fill Ev: Ev[m,y] = exp(-i * kv[m] * (y-128)) = (cos, -sin)
    for (int idx = tid; idx < TM * NPIX; idx += 256) {
        const int m = idx >> 8;
        const int y = idx & 255;
        const float ph = ktraj[m0 + m] * (float)(y - 128);
        float s, c;
        sincosf(ph, &s, &c);
        float2 e; e.x = c; e.y = -s;
        *(float2*)&ev[idx * 2] = e;
    }

    // Eu in registers: Eu[m,x] = exp(-i * ku[m] * (x-128))
    float eur[MT][XT], eui[MT][XT];
    #pragma unroll
    for (int mi = 0; mi < MT; ++mi) {
        const float ku = ktraj[MM + m0 + mg * MT + mi];
        #pragma unroll
        for (int xi = 0; xi < XT; ++xi) {
            float s, c;
            sincosf(ku * (float)(x0 + xi - 128), &s, &c);
            eur[mi][xi] = c; eui[mi][xi] = -s;
        }
    }
    __syncthreads();

    for (int b = 0; b < BB; ++b) {
        float ar[MT][XT] = {};
        float ai[MT][XT] = {};
        const float* imgb = images + b * NPIX * NPIX + x0;

        #pragma unroll 2
        for (int y = 0; y < NPIX; y += 2) {
            float v0[8], v1[8];
            float4 t0 = *(const float4*)(imgb + y * NPIX);
            float4 t1 = *(const float4*)(imgb + y * NPIX + 4);
            float4 t2 = *(const float4*)(imgb + (y + 1) * NPIX);
            float4 t3 = *(const float4*)(imgb + (y + 1) * NPIX + 4);
            v0[0]=t0.x; v0[1]=t0.y; v0[2]=t0.z; v0[3]=t0.w;
            v0[4]=t1.x; v0[5]=t1.y; v0[6]=t1.z; v0[7]=t1.w;
            v1[0]=t2.x; v1[1]=t2.y; v1[2]=t2.z; v1[3]=t2.w;
            v1[4]=t3.x; v1[5]=t3.y; v1[6]=t3.z; v1[7]=t3.w;

            #pragma unroll
            for (int mi = 0; mi < MT; ++mi) {
                const int m = mg * MT + mi;
                // (re_y, im_y, re_{y+1}, im_{y+1}) — broadcast read, conflict-free
                const float4 e = *(const float4*)&ev[((m << 8) + y) * 2];
                #pragma unroll
                for (int xi = 0; xi < XT; ++xi) {
                    ar[mi][xi] = fmaf(v0[xi], e.x, ar[mi][xi]);
                    ai[mi][xi] = fmaf(v0[xi], e.y, ai[mi][xi]);
                    ar[mi][xi] = fmaf(v1[xi], e.z, ar[mi][xi]);
                    ai[mi][xi] = fmaf(v1[xi], e.w, ai[mi][xi]);
                }
            }
        }

        // Epilogue: tmp * Eu, reduce over x (in-thread 8, then 32 lanes)
        #pragma unroll
        for (int mi = 0; mi < MT; ++mi) {
            float sr = 0.f, si = 0.f;
            #pragma unroll
            for (int xi = 0; xi < XT; ++xi) {
                sr += ar[mi][xi] * eur[mi][xi] - ai[mi][xi] * eui[mi][xi];
                si += ar[mi][xi] * eui[mi][xi] + ai[mi][xi] * eur[mi][xi];
            }
            // butterfly over the 32 lanes sharing this m (masks<32 stay in-half)
            #pragma unroll
            for (int off = 16; off >= 1; off >>= 1) {
                sr += __shfl_xor(sr, off);
                si += __shfl_xor(si, off);
            }
            if (xg == 0) {
                const int m = m0 + mg * MT + mi;
                const float pr = pulsefac[m];
                const float pi = pulsefac[MM + m];
                const float vr = sr * pr - si * pi;
                const float vi = sr * pi + si * pr;
                out[b * 2 * MM + m]      = vr;             // vis[b,0,m]
                out[b * 2 * MM + MM + m] = vi;             // vis[b,1,m]
                out[VISAMP_OFF + b * MM + m] = sqrtf(vr * vr + vi * vi + EPSF);
            }
        }
    }
}

__global__ void cphase_kernel(const float* __restrict__ vis,
                              const float* __restrict__ sign,
                              const int* __restrict__ ind,
                              float* __restrict__ out)
{
    const int i = blockIdx.x * blockDim.x + threadIdx.x;
    if (i >= BB * NCP) return;
    const int b = i / NCP;
    const int n = i - b * NCP;
    float acc = 0.f;
    #pragma unroll
    for (int k = 0; k < 3; ++k) {
        const int m = ind[k * NCP + n];
        const float vr = vis[b * 2 * MM + m];
        const float vi = vis[b * 2 * MM + MM + m];
        acc += sign[k * NCP + n] * atan2f(vi, vr);
    }
    out[CPH_OFF + i] = acc * 57.295779513082323f;   // 180/pi
}

__global__ void logcamp_kernel(const float* __restrict__ vis,
                               const int* __restrict__ ind,
                               float* __restrict__ out)
{
    const int i = blockIdx.x * blockDim.x + threadIdx.x;
    if (i >= BB * NCA) return;
    const int b = i / NCA;
    const int n = i - b * NCA;
    float acc = 0.f;
    #pragma unroll
    for (int k = 0; k < 4; ++k) {
        const int m = ind[k * NCA + n];
        const float vr = vis[b * 2 * MM + m];
        const float vi = vis[b * 2 * MM + MM + m];
        const float a = sqrtf(vr * vr + vi * vi + EPSF);
        acc += (k < 2 ? 1.f : -1.f) * logf(a);
    }
    out[LCA_OFF + i] = acc;
}

extern "C" void kernel_launch(void* const* d_in, const int* in_sizes, int n_in,
                              void* d_out, int out_size, void* d_ws, size_t ws_size,
                              hipStream_t stream)
{
    const float* images   = (const float*)d_in[0];
    const float* ktraj    = (const float*)d_in[1];
    const float* pulsefac = (const float*)d_in[2];
    const float* csign    = (const float*)d_in[3];
    const int*   cind     = (const int*)d_in[4];
    const int*   caind    = (const int*)d_in[5];
    float* out = (float*)d_out;

    nufft_vis_kernel<<<MM / TM, 256, 0, stream>>>(images, ktraj, pulsefac, out);
    cphase_kernel<<<(BB * NCP + 255) / 256, 256, 0, stream>>>(out, csign, cind, out);
    logcamp_kernel<<<(BB * NCA + 255) / 256, 256, 0, stream>>>(out, caind, out);
}

// Round 2
// 302.792 us; speedup vs baseline: 1.4684x; 1.4684x over previous
//
#include <hip/hip_runtime.h>
#include <cmath>

#define BB   8
#define NPIX 256
#define MM   8192
#define NCP  24576
#define NCA  24576
#define EPSF 1e-16f

#define TM 16    // m's per block
#define MT 4     // m's per thread (4 m-groups = 4 waves)
#define XT 4     // x's per thread (64 x-groups = 1 wave-width)

#define VIS_OFF    0
#define VISAMP_OFF (BB * 2 * MM)            // 131072
#define CPH_OFF    (VISAMP_OFF + BB * MM)   // 196608
#define LCA_OFF    (CPH_OFF + BB * NCP)     // 393216

// Main kernel: computes vis (B,2,M) and visamp (B,M) into d_out.
// Grid: (MM/TM, 2); each block handles 16 m's x 4 batches.
__global__ __launch_bounds__(256, 4)
void nufft_vis_kernel(const float* __restrict__ images,
                      const float* __restrict__ ktraj,
                      const float* __restrict__ pulsefac,
                      float* __restrict__ out)
{
    // Ev table: [m][y][re/im] interleaved, 16*256*2 floats = 32 KB
    __shared__ float ev[TM * NPIX * 2];

    const int tid = threadIdx.x;
    const int m0  = blockIdx.x * TM;
    const int b0  = blockIdx.y * 4;
    const int xg  = tid & 63;     // x-group (lane)
    const int mg  = tid >> 6;     // m-group == wave id
    const int x0  = xg * XT;

    // Fill Ev: Ev[m,y] = exp(-i * kv[m] * (y-128)) = (cos, -sin)
    for (int idx = tid; idx < TM * NPIX; idx += 256) {
        const int m = idx >> 8;
        const int y = idx & 255;
        const float ph = ktraj[m0 + m] * (float)(y - 128);
        float s, c;
        sincosf(ph, &s, &c);
        float2 e; e.x = c; e.y = -s;
        *(float2*)&ev[idx * 2] = e;
    }

    // Eu in registers: Eu[m,x] = exp(-i * ku[m] * (x-128))
    float eur[MT][XT], eui[MT][XT];
    #pragma unroll
    for (int mi = 0; mi < MT; ++mi) {
        const float ku = ktraj[MM + m0 + mg * MT + mi];
        #pragma unroll
        for (int xi = 0; xi < XT; ++xi) {
            float s, c;
            sincosf(ku * (float)(x0 + xi - 128), &s, &c);
            eur[mi][xi] = c; eui[mi][xi] = -s;
        }
    }
    __syncthreads();

    for (int b = b0; b < b0 + 4; ++b) {
        float ar[MT][XT] = {};
        float ai[MT][XT] = {};
        const float* imgb = images + b * NPIX * NPIX + x0;

        for (int y = 0; y < NPIX; y += 4) {
            float vv[4][XT];
            *(float4*)vv[0] = *(const float4*)(imgb + (y + 0) * NPIX);
            *(float4*)vv[1] = *(const float4*)(imgb + (y + 1) * NPIX);
            *(float4*)vv[2] = *(const float4*)(imgb + (y + 2) * NPIX);
            *(float4*)vv[3] = *(const float4*)(imgb + (y + 3) * NPIX);

            #pragma unroll
            for (int mi = 0; mi < MT; ++mi) {
                const int ml = mg * MT + mi;
                // broadcast reads (all 64 lanes same addr) — conflict-free
                const float4 ea = *(const float4*)&ev[(ml * NPIX + y) * 2];
                const float4 eb = *(const float4*)&ev[(ml * NPIX + y + 2) * 2];
                const float er[4] = {ea.x, ea.z, eb.x, eb.z};
                const float ei[4] = {ea.y, ea.w, eb.y, eb.w};
                #pragma unroll
                for (int yi = 0; yi < 4; ++yi) {
                    #pragma unroll
                    for (int xi = 0; xi < XT; ++xi) {
                        ar[mi][xi] = fmaf(vv[yi][xi], er[yi], ar[mi][xi]);
                        ai[mi][xi] = fmaf(vv[yi][xi], ei[yi], ai[mi][xi]);
                    }
                }
            }
        }

        // Epilogue: tmp * Eu, reduce over x (in-thread 4, then 64 lanes)
        #pragma unroll
        for (int mi = 0; mi < MT; ++mi) {
            float sr = 0.f, si = 0.f;
            #pragma unroll
            for (int xi = 0; xi < XT; ++xi) {
                sr += ar[mi][xi] * eur[mi][xi] - ai[mi][xi] * eui[mi][xi];
                si += ar[mi][xi] * eui[mi][xi] + ai[mi][xi] * eur[mi][xi];
            }
            // full-wave butterfly (64 lanes, one m per wave)
            #pragma unroll
            for (int off = 32; off >= 1; off >>= 1) {
                sr += __shfl_xor(sr, off);
                si += __shfl_xor(si, off);
            }
            if (xg == 0) {
                const int m = m0 + mg * MT + mi;
                const float pr = pulsefac[m];
                const float pi = pulsefac[MM + m];
                const float vr = sr * pr - si * pi;
                const float vi = sr * pi + si * pr;
                out[b * 2 * MM + m]      = vr;             // vis[b,0,m]
                out[b * 2 * MM + MM + m] = vi;             // vis[b,1,m]
                out[VISAMP_OFF + b * MM + m] = sqrtf(vr * vr + vi * vi + EPSF);
            }
        }
    }
}

__global__ void cphase_kernel(const float* __restrict__ vis,
                              const float* __restrict__ sign,
                              const int* __restrict__ ind,
                              float* __restrict__ out)
{
    const int i = blockIdx.x * blockDim.x + threadIdx.x;
    if (i >= BB * NCP) return;
    const int b = i / NCP;
    const int n = i - b * NCP;
    float acc = 0.f;
    #pragma unroll
    for (int k = 0; k < 3; ++k) {
        const int m = ind[k * NCP + n];
        const float vr = vis[b * 2 * MM + m];
        const float vi = vis[b * 2 * MM + MM + m];
        acc += sign[k * NCP + n] * atan2f(vi, vr);
    }
    out[CPH_OFF + i] = acc * 57.295779513082323f;   // 180/pi
}

__global__ void logcamp_kernel(const float* __restrict__ vis,
                               const int* __restrict__ ind,
                               float* __restrict__ out)
{
    const int i = blockIdx.x * blockDim.x + threadIdx.x;
    if (i >= BB * NCA) return;
    const int b = i / NCA;
    const int n = i - b * NCA;
    float acc = 0.f;
    #pragma unroll
    for (int k = 0; k < 4; ++k) {
        const int m = ind[k * NCA + n];
        const float vr = vis[b * 2 * MM + m];
        const float vi = vis[b * 2 * MM + MM + m];
        const float a = sqrtf(vr * vr + vi * vi + EPSF);
        acc += (k < 2 ? 1.f : -1.f) * logf(a);
    }
    out[LCA_OFF + i] = acc;
}

extern "C" void kernel_launch(void* const* d_in, const int* in_sizes, int n_in,
                              void* d_out, int out_size, void* d_ws, size_t ws_size,
                              hipStream_t stream)
{
    const float* images   = (const float*)d_in[0];
    const float* ktraj    = (const float*)d_in[1];
    const float* pulsefac = (const float*)d_in[2];
    const float* csign    = (const float*)d_in[3];
    const int*   cind     = (const int*)d_in[4];
    const int*   caind    = (const int*)d_in[5];
    float* out = (float*)d_out;

    dim3 grid(MM / TM, 2);
    nufft_vis_kernel<<<grid, 256, 0, stream>>>(images, ktraj, pulsefac, out);
    cphase_kernel<<<(BB * NCP + 255) / 256, 256, 0, stream>>>(out, csign, cind, out);
    logcamp_kernel<<<(BB * NCA + 255) / 256, 256, 0, stream>>>(out, caind, out);
}

// Round 4
// 125.547 us; speedup vs baseline: 3.5415x; 2.4118x over previous
//
#include <hip/hip_runtime.h>
#include <cmath>

#define BB   8
#define NPIX 256
#define MM   8192
#define NCP  24576
#define NCA  24576
#define EPSF 1e-16f

#define KC   32    // K-chunk (y's per chunk)
#define KCW  40    // padded LDS row width (elements); 80 B rows, 16B-aligned
#define TMB  64    // m's per block

#define VIS_OFF    0
#define VISAMP_OFF (BB * 2 * MM)            // 131072
#define CPH_OFF    (VISAMP_OFF + BB * MM)   // 196608
#define LCA_OFF    (CPH_OFF + BB * NCP)     // 393216

typedef __bf16 bf16x8 __attribute__((ext_vector_type(8)));
typedef float  f32x4  __attribute__((ext_vector_type(4)));

// Block: 64 m's x 256 x's x 1 batch. Wave w owns m-span [16w,16w+16) and
// accumulates BOTH real (Evr rows) and imag (Evi rows) planes, so the
// epilogue is fully in-wave (no cross-wave LDS combine).
// 3-term bf16 split (hh, hl, lh) per plane.
__global__ __launch_bounds__(256, 2)
void nufft_vis_mfma(const float* __restrict__ images,
                    const float* __restrict__ ktraj,
                    const float* __restrict__ pulsefac,
                    float* __restrict__ out)
{
    __shared__ __align__(16) __bf16 sA_hi[128 * KCW];   // rows 0..63 Evr, 64..127 Evi
    __shared__ __align__(16) __bf16 sA_lo[128 * KCW];
    __shared__ __align__(16) __bf16 sB_hi[NPIX * KCW];  // rows: x; cols: k
    __shared__ __align__(16) __bf16 sB_lo[NPIX * KCW];

    const int tid  = threadIdx.x;
    const int m0   = blockIdx.x * TMB;
    const int b    = blockIdx.y;
    const int lane = tid & 63;
    const int w    = tid >> 6;        // wave 0..3
    const int ln15 = lane & 15;
    const int q    = lane >> 4;       // quad 0..3

    // staging roles: thread (am, ajg) stages Ev rows for m=am, k-octet ajg
    const int am  = tid >> 2;
    const int ajg = tid & 3;
    const float kvm = ktraj[m0 + am];
    float rots, rotc;                  // rotor e^{-i*kvm} = (rotc, -rots)
    sincosf(kvm, &rots, &rotc);
    const float* imgb = images + b * NPIX * NPIX + tid;  // B-staging: x = tid

    f32x4 acc[2][16];                  // [0]=real plane, [1]=imag plane
    #pragma unroll
    for (int rt = 0; rt < 2; ++rt)
        #pragma unroll
        for (int ct = 0; ct < 16; ++ct)
            acc[rt][ct] = (f32x4){0.f, 0.f, 0.f, 0.f};

    for (int y0 = 0; y0 < NPIX; y0 += KC) {
        // ---- stage A: Ev[m, y0+8*ajg .. +8) via anchored sincos + rotor
        {
            float s, c;
            sincosf(kvm * (float)(y0 + ajg * 8 - 128), &s, &c);
            float er = c, ei = -s;     // Ev = exp(-i*kv*(y-128))
            bf16x8 vrh, vrl, vih, vil;
            #pragma unroll
            for (int j = 0; j < 8; ++j) {
                __bf16 h = (__bf16)er;
                vrh[j] = h; vrl[j] = (__bf16)(er - (float)h);
                h = (__bf16)ei;
                vih[j] = h; vil[j] = (__bf16)(ei - (float)h);
                const float nr = er * rotc + ei * rots;   // *= e^{-i*kvm}
                const float ni = ei * rotc - er * rots;
                er = nr; ei = ni;
            }
            *(bf16x8*)&sA_hi[am * KCW + ajg * 8]        = vrh;
            *(bf16x8*)&sA_lo[am * KCW + ajg * 8]        = vrl;
            *(bf16x8*)&sA_hi[(64 + am) * KCW + ajg * 8] = vih;
            *(bf16x8*)&sA_lo[(64 + am) * KCW + ajg * 8] = vil;
        }
        // ---- stage B: img[b, y0..y0+31, x=tid] transposed -> [x][k] hi/lo
        #pragma unroll
        for (int g = 0; g < 4; ++g) {
            bf16x8 bh, bl;
            #pragma unroll
            for (int j = 0; j < 8; ++j) {
                const float v = imgb[(y0 + g * 8 + j) * NPIX];
                const __bf16 h = (__bf16)v;
                bh[j] = h; bl[j] = (__bf16)(v - (float)h);
            }
            *(bf16x8*)&sB_hi[tid * KCW + g * 8] = bh;
            *(bf16x8*)&sB_lo[tid * KCW + g * 8] = bl;
        }
        __syncthreads();

        // ---- MFMA: wave w reads Evr rows [16w,16w+16) and Evi rows [64+16w, ..)
        bf16x8 a_h[2], a_l[2];
        const int ar0 = w * 16 + ln15;
        a_h[0] = *(const bf16x8*)&sA_hi[ar0 * KCW + q * 8];
        a_l[0] = *(const bf16x8*)&sA_lo[ar0 * KCW + q * 8];
        a_h[1] = *(const bf16x8*)&sA_hi[(64 + ar0) * KCW + q * 8];
        a_l[1] = *(const bf16x8*)&sA_lo[(64 + ar0) * KCW + q * 8];

        #pragma unroll
        for (int ct = 0; ct < 16; ++ct) {
            const int brow = ct * 16 + ln15;
            const bf16x8 bh = *(const bf16x8*)&sB_hi[brow * KCW + q * 8];
            const bf16x8 bl = *(const bf16x8*)&sB_lo[brow * KCW + q * 8];
            #pragma unroll
            for (int rt = 0; rt < 2; ++rt) {
                acc[rt][ct] = __builtin_amdgcn_mfma_f32_16x16x32_bf16(a_h[rt], bh, acc[rt][ct], 0, 0, 0);
                acc[rt][ct] = __builtin_amdgcn_mfma_f32_16x16x32_bf16(a_h[rt], bl, acc[rt][ct], 0, 0, 0);
                acc[rt][ct] = __builtin_amdgcn_mfma_f32_16x16x32_bf16(a_l[rt], bh, acc[rt][ct], 0, 0, 0);
            }
        }
        __syncthreads();
    }

    // ---- fused stage 2 (all in-wave): kdata[b,m] = sum_x tmp[m,x] * Eu[m,x]
    // C layout: col(x within tile) = ln15, row(m within tile) = 4*q + r
    #pragma unroll
    for (int r = 0; r < 4; ++r) {
        const int m = m0 + w * 16 + q * 4 + r;
        const float ku = ktraj[MM + m];
        float s0, c0, s16, c16;
        sincosf(ku * (float)(ln15 - 128), &s0, &c0);
        sincosf(ku * 16.0f, &s16, &c16);
        float er = c0, ei = -s0;       // Eu at x = ln15 - 128, step +16 per ct
        float sr = 0.f, si = 0.f;
        #pragma unroll
        for (int ct = 0; ct < 16; ++ct) {
            const float tr = acc[0][ct][r];
            const float ti = acc[1][ct][r];
            sr = fmaf(tr, er, fmaf(-ti, ei, sr));
            si = fmaf(tr, ei, fmaf(ti, er, si));
            const float nr = er * c16 + ei * s16;   // *= e^{-i*ku*16}
            const float ni = ei * c16 - er * s16;
            er = nr; ei = ni;
        }
        // reduce over the 16 lanes of this quad (masks <16 stay in-quad)
        #pragma unroll
        for (int off = 8; off >= 1; off >>= 1) {
            sr += __shfl_xor(sr, off);
            si += __shfl_xor(si, off);
        }
        if (ln15 == 0) {
            const float pr = pulsefac[m];
            const float pi = pulsefac[MM + m];
            const float vr = sr * pr - si * pi;
            const float vi = sr * pi + si * pr;
            out[b * 2 * MM + m]      = vr;
            out[b * 2 * MM + MM + m] = vi;
            out[VISAMP_OFF + b * MM + m] = sqrtf(vr * vr + vi * vi + EPSF);
        }
    }
}

__global__ void cphase_kernel(const float* __restrict__ vis,
                              const float* __restrict__ sign,
                              const int* __restrict__ ind,
                              float* __restrict__ out)
{
    const int i = blockIdx.x * blockDim.x + threadIdx.x;
    if (i >= BB * NCP) return;
    const int b = i / NCP;
    const int n = i - b * NCP;
    float acc = 0.f;
    #pragma unroll
    for (int k = 0; k < 3; ++k) {
        const int m = ind[k * NCP + n];
        const float vr = vis[b * 2 * MM + m];
        const float vi = vis[b * 2 * MM + MM + m];
        acc += sign[k * NCP + n] * atan2f(vi, vr);
    }
    out[CPH_OFF + i] = acc * 57.295779513082323f;   // 180/pi
}

__global__ void logcamp_kernel(const float* __restrict__ vis,
                               const int* __restrict__ ind,
                               float* __restrict__ out)
{
    const int i = blockIdx.x * blockDim.x + threadIdx.x;
    if (i >= BB * NCA) return;
    const int b = i / NCA;
    const int n = i - b * NCA;
    float acc = 0.f;
    #pragma unroll
    for (int k = 0; k < 4; ++k) {
        const int m = ind[k * NCA + n];
        const float vr = vis[b * 2 * MM + m];
        const float vi = vis[b * 2 * MM + MM + m];
        const float a = sqrtf(vr * vr + vi * vi + EPSF);
        acc += (k < 2 ? 1.f : -1.f) * logf(a);
    }
    out[LCA_OFF + i] = acc;
}

extern "C" void kernel_launch(void* const* d_in, const int* in_sizes, int n_in,
                              void* d_out, int out_size, void* d_ws, size_t ws_size,
                              hipStream_t stream)
{
    const float* images   = (const float*)d_in[0];
    const float* ktraj    = (const float*)d_in[1];
    const float* pulsefac = (const float*)d_in[2];
    const float* csign    = (const float*)d_in[3];
    const int*   cind     = (const int*)d_in[4];
    const int*   caind    = (const int*)d_in[5];
    float* out = (float*)d_out;

    dim3 grid(MM / TMB, BB);
    nufft_vis_mfma<<<grid, 256, 0, stream>>>(images, ktraj, pulsefac, out);
    cphase_kernel<<<(BB * NCP + 255) / 256, 256, 0, stream>>>(out, csign, cind, out);
    logcamp_kernel<<<(BB * NCA + 255) / 256, 256, 0, stream>>>(out, caind, out);
}